// Round 7
// baseline (108.196 us; speedup 1.0000x reference)
//
#include <hip/hip_runtime.h>

// HEGN loss: L_reg + bidirectional chamfer(x, y).  B=8, N=M=4096.
#define BB 8
#define NN 4096
#define MC 64                     // reference points staged per chunk
#define NCHUNK (NN / MC)          // 64
#define KPT 8                     // query points per thread (4 packed pairs)
#define TPB 128                   // two waves per block
#define PTS_PER_BLOCK (TPB * KPT) // 1024
#define NPTS (2 * BB * NN)        // 65536 (both directions)

// ws layout: nnmin[zb][p] as uint-ordered floats, 65536 entries = 256 KB.
// Initialized to 0x7F7F7F7F (3.39e38) by hipMemsetAsync; atomicMin on the
// uint bit pattern == fmin for non-negative floats (d2 clamped >= 0).

typedef __attribute__((ext_vector_type(2))) float f2;

// VOP3P op_sel broadcast variants: src1 (ref coord pair) broadcast from its
// lo or hi half into both result halves; src0 (packed queries) normal.
// _bc: src2 also broadcast (the packed |r|^2 pair); _b: src2 normal (chain).
__device__ __forceinline__ f2 pk_fma_lo_bc(f2 a, f2 b, f2 c) {
  f2 d;
  asm("v_pk_fma_f32 %0, %1, %2, %3 op_sel:[0,0,0] op_sel_hi:[1,0,0]"
      : "=v"(d) : "v"(a), "v"(b), "v"(c));
  return d;
}
__device__ __forceinline__ f2 pk_fma_lo_b(f2 a, f2 b, f2 c) {
  f2 d;
  asm("v_pk_fma_f32 %0, %1, %2, %3 op_sel:[0,0,0] op_sel_hi:[1,0,1]"
      : "=v"(d) : "v"(a), "v"(b), "v"(c));
  return d;
}
__device__ __forceinline__ f2 pk_fma_hi_bc(f2 a, f2 b, f2 c) {
  f2 d;
  asm("v_pk_fma_f32 %0, %1, %2, %3 op_sel:[0,1,1] op_sel_hi:[1,1,1]"
      : "=v"(d) : "v"(a), "v"(b), "v"(c));
  return d;
}
__device__ __forceinline__ f2 pk_fma_hi_b(f2 a, f2 b, f2 c) {
  f2 d;
  asm("v_pk_fma_f32 %0, %1, %2, %3 op_sel:[0,1,0] op_sel_hi:[1,1,1]"
      : "=v"(d) : "v"(a), "v"(b), "v"(c));
  return d;
}

__global__ __launch_bounds__(TPB, 8) void chamfer_partial(
    const float* __restrict__ X, const float* __restrict__ Y,
    unsigned int* __restrict__ nnmin, float* __restrict__ out) {
  // Pair-packed staging: lxy[jp]=(-2x0,-2x1,-2y0,-2y1), lzw[jp]=(-2z0,-2z1,|r0|^2,|r1|^2)
  __shared__ float4 lxy[MC / 2];
  __shared__ float4 lzw[MC / 2];
  const int tid = threadIdx.x;
  const int zb  = blockIdx.z;     // (dir<<3) | b
  const int b   = zb & (BB - 1);
  const int dir = zb >> 3;
  const float* pts  = dir ? (Y + b * NN * 3) : (X + b * NN * 3);
  const float* refs = dir ? (X + b * NN * 3) : (Y + b * NN * 3);
  const int c = blockIdx.y;

  // Zero the output once; stream order guarantees this lands before
  // chamfer_reduce's atomics.
  if (blockIdx.x == 0 && blockIdx.y == 0 && blockIdx.z == 0 && tid == 0)
    out[0] = 0.0f;

  if (tid < MC / 2) {
    const int j = c * MC + 2 * tid;
    const float a0 = refs[j * 3 + 0], a1 = refs[j * 3 + 1], a2 = refs[j * 3 + 2];
    const float b0 = refs[j * 3 + 3], b1 = refs[j * 3 + 4], b2 = refs[j * 3 + 5];
    lxy[tid] = make_float4(-2.0f * a0, -2.0f * b0, -2.0f * a1, -2.0f * b1);
    lzw[tid] = make_float4(-2.0f * a2, -2.0f * b2,
                           a0 * a0 + a1 * a1 + a2 * a2,
                           b0 * b0 + b1 * b1 + b2 * b2);
  }

  // Queries packed two-per-register-pair (no duplication): 12 VGPRs total.
  f2 qx[KPT / 2], qy[KPT / 2], qz[KPT / 2], m2[KPT / 2];
  const int p0 = blockIdx.x * PTS_PER_BLOCK + tid;
#pragma unroll
  for (int i = 0; i < KPT / 2; i++) {
    const int pa = p0 + (2 * i) * TPB;
    const int pb = p0 + (2 * i + 1) * TPB;
    qx[i] = (f2){pts[pa * 3 + 0], pts[pb * 3 + 0]};
    qy[i] = (f2){pts[pa * 3 + 1], pts[pb * 3 + 1]};
    qz[i] = (f2){pts[pa * 3 + 2], pts[pb * 3 + 2]};
    m2[i] = (f2){1e30f, 1e30f};
  }
  __syncthreads();

  // min over chunk of (|r|^2 - 2 q.r): 2 refs x 2 packed queries per i-step.
  // Ref coords broadcast straight out of the LDS float4 halves via op_sel.
#pragma unroll 2
  for (int jp = 0; jp < MC / 2; jp++) {
    const float4 wxy = lxy[jp];
    const float4 wzw = lzw[jp];
    const f2 Px = (f2){wxy.x, wxy.y};
    const f2 Py = (f2){wxy.z, wxy.w};
    const f2 Pz = (f2){wzw.x, wzw.y};
    const f2 Pw = (f2){wzw.z, wzw.w};
#pragma unroll
    for (int i = 0; i < KPT / 2; i++) {
      f2 s = pk_fma_lo_bc(qz[i], Pz, Pw);   // ref j0 vs queries (k0,k1)
      s = pk_fma_lo_b(qy[i], Py, s);
      s = pk_fma_lo_b(qx[i], Px, s);
      f2 t = pk_fma_hi_bc(qz[i], Pz, Pw);   // ref j1 vs queries (k0,k1)
      t = pk_fma_hi_b(qy[i], Py, t);
      t = pk_fma_hi_b(qx[i], Px, t);
      m2[i].x = fminf(m2[i].x, fminf(s.x, t.x));   // -> v_min3_f32
      m2[i].y = fminf(m2[i].y, fminf(s.y, t.y));   // -> v_min3_f32
    }
  }

#pragma unroll
  for (int i = 0; i < KPT / 2; i++) {
    const int pa = p0 + (2 * i) * TPB;
    const int pb = p0 + (2 * i + 1) * TPB;
    const float na = qx[i].x * qx[i].x + qy[i].x * qy[i].x + qz[i].x * qz[i].x;
    const float nb = qx[i].y * qx[i].y + qy[i].y * qy[i].y + qz[i].y * qz[i].y;
    const float da = fmaxf(m2[i].x + na, 0.0f);  // clamp keeps uint-order == float-order
    const float db = fmaxf(m2[i].y + nb, 0.0f);
    atomicMin(&nnmin[zb * NN + pa], __float_as_uint(da));
    atomicMin(&nnmin[zb * NN + pb], __float_as_uint(db));
  }
}

// Sum the 64K per-point NN mins (256 KB), 1 atomic per block into out
// (zeroed by chamfer_partial upstream).  Block 0 also adds L_reg.
__global__ __launch_bounds__(256) void chamfer_reduce(
    const float* __restrict__ nnmin,
    const float* __restrict__ R, const float* __restrict__ S,
    const float* __restrict__ t, const float* __restrict__ Rgt,
    const float* __restrict__ Sgt, const float* __restrict__ tgt,
    float* __restrict__ out) {
  const int tid = threadIdx.x;
  const int base = blockIdx.x * 2048;        // 32 blocks cover NPTS
  const float4* v = (const float4*)nnmin;
  const float4 a0 = v[(base >> 2) + tid];
  const float4 a1 = v[(base >> 2) + 256 + tid];
  float s = (a0.x + a0.y) + (a0.z + a0.w) + (a1.x + a1.y) + (a1.z + a1.w);
  for (int o = 32; o > 0; o >>= 1) s += __shfl_down(s, o);
  __shared__ float wsum[4];
  if ((tid & 63) == 0) wsum[tid >> 6] = s;
  __syncthreads();
  if (tid == 0) {
    const float bs = wsum[0] + wsum[1] + wsum[2] + wsum[3];
    atomicAdd(out, bs * (1.0f / (float)(BB * NN)));
  }

  if (blockIdx.x == 0) {
    float v2 = 0.0f;
    if (tid < 72) {                       // R @ R_gt^T - I, squared
      const int b = tid / 9, ik = tid % 9, i = ik / 3, k = ik % 3;
      const float* Rb = R + b * 9;
      const float* Gb = Rgt + b * 9;
      float d = Rb[i * 3 + 0] * Gb[k * 3 + 0] +
                Rb[i * 3 + 1] * Gb[k * 3 + 1] +
                Rb[i * 3 + 2] * Gb[k * 3 + 2];
      d -= (i == k) ? 1.0f : 0.0f;
      v2 = d * d;
    } else if (tid < 96) {                // (S - S_gt)^2
      const int i = tid - 72;
      const float d = S[i] - Sgt[i];
      v2 = d * d;
    } else if (tid < 120) {               // (t - t_gt)^2
      const int i = tid - 96;
      const float d = t[i] - tgt[i];
      v2 = d * d;
    }
    for (int o = 32; o > 0; o >>= 1) v2 += __shfl_down(v2, o);
    __shared__ float rsum[4];
    if ((tid & 63) == 0) rsum[tid >> 6] = v2;
    __syncthreads();
    if (tid == 0) atomicAdd(out, rsum[0] + rsum[1] + rsum[2] + rsum[3]);
  }
}

extern "C" void kernel_launch(void* const* d_in, const int* in_sizes, int n_in,
                              void* d_out, int out_size, void* d_ws, size_t ws_size,
                              hipStream_t stream) {
  const float* X   = (const float*)d_in[0];
  const float* Y   = (const float*)d_in[1];
  const float* R   = (const float*)d_in[2];
  const float* S   = (const float*)d_in[3];
  const float* t   = (const float*)d_in[4];
  const float* Rgt = (const float*)d_in[5];
  const float* Sgt = (const float*)d_in[6];
  const float* tgt = (const float*)d_in[7];

  unsigned int* nnmin = (unsigned int*)d_ws;
  float* out = (float*)d_out;

  // 0x7F7F7F7F == 3.39e38f: valid "+inf-like" init for uint-ordered fmin.
  hipMemsetAsync(nnmin, 0x7F, NPTS * sizeof(unsigned int), stream);

  dim3 gA(NN / PTS_PER_BLOCK, NCHUNK, 2 * BB);   // (4, 64, 16) = 4096 blocks, 8 waves/SIMD
  chamfer_partial<<<gA, TPB, 0, stream>>>(X, Y, nnmin, out);

  chamfer_reduce<<<NPTS / 2048, 256, 0, stream>>>((const float*)nnmin,
                                                  R, S, t, Rgt, Sgt, tgt, out);
}